// Round 13
// baseline (515.795 us; speedup 1.0000x reference)
//
#include <hip/hip_runtime.h>
#include <hip/hip_bf16.h>
#include <stdint.h>

#define B_ 8
#define S_ 2048
#define F_ 512
#define E_ 512

typedef short bf16x8 __attribute__((ext_vector_type(8)));
typedef float f32x4 __attribute__((ext_vector_type(4)));

__device__ __forceinline__ f32x4 mfma16(bf16x8 a, bf16x8 b, f32x4 c) {
  return __builtin_amdgcn_mfma_f32_16x16x32_bf16(a, b, c, 0, 0, 0);
}

// async global->LDS, 16B per lane; dst is wave-uniform base, src per-lane
__device__ __forceinline__ void gll16(const void* g, void* l) {
  __builtin_amdgcn_global_load_lds(
      (const __attribute__((address_space(1))) void*)g,
      (__attribute__((address_space(3))) void*)l, 16, 0, 0);
}

// softmax scale folded into Q at projection time: log2(e)/sqrt(E)
constexpr float QSCALE = 0.0441941738f * 1.44269504f;

// ---------------- kernel A: x fp32 -> bf16 ----------------
__global__ void xconv_kernel(const float* __restrict__ x,
                             __hip_bfloat16* __restrict__ xb) {
  int i = (blockIdx.x * 256 + threadIdx.x) * 8;
  float4 a = *(const float4*)(x + i);
  float4 b = *(const float4*)(x + i + 4);
  union { __hip_bfloat16 h[8]; uint4 u; } cv;
  cv.h[0] = __float2bfloat16(a.x);
  cv.h[1] = __float2bfloat16(a.y);
  cv.h[2] = __float2bfloat16(a.z);
  cv.h[3] = __float2bfloat16(a.w);
  cv.h[4] = __float2bfloat16(b.x);
  cv.h[5] = __float2bfloat16(b.y);
  cv.h[6] = __float2bfloat16(b.z);
  cv.h[7] = __float2bfloat16(b.w);
  *(uint4*)(xb + i) = cv.u;
}

// ---------------- kernel 0: W[f][e] fp32 -> Wt[e][f] bf16 (x3) ----------------
__global__ void wtrans_kernel(const float* __restrict__ wq,
                              const float* __restrict__ wk,
                              const float* __restrict__ wv,
                              __hip_bfloat16* __restrict__ wt) {
  __shared__ float t[32][33];
  const float* w = (blockIdx.z == 0) ? wq : (blockIdx.z == 1 ? wk : wv);
  __hip_bfloat16* o = wt + (size_t)blockIdx.z * F_ * E_;
  int e0 = blockIdx.x * 32, f0 = blockIdx.y * 32;
  int tx = threadIdx.x, ty = threadIdx.y;
#pragma unroll
  for (int i = 0; i < 4; i++)
    t[ty + 8 * i][tx] = w[(size_t)(f0 + ty + 8 * i) * E_ + e0 + tx];
  __syncthreads();
#pragma unroll
  for (int i = 0; i < 4; i++)
    o[(size_t)(e0 + ty + 8 * i) * F_ + f0 + tx] = __float2bfloat16(t[tx][ty + 8 * i]);
}

// ---------------- kernel 1: QKV projection GEMM, gll16-staged ----------------
__global__ __launch_bounds__(256, 2) void qkvg_kernel(
    const __hip_bfloat16* __restrict__ xb, const __hip_bfloat16* __restrict__ wt,
    __hip_bfloat16* __restrict__ Qb, __hip_bfloat16* __restrict__ Kb,
    __hip_bfloat16* __restrict__ Vt) {
  __shared__ __hip_bfloat16 Al[2][128][64] __attribute__((aligned(16)));
  __shared__ __hip_bfloat16 Bl[2][128][64] __attribute__((aligned(16)));

  int tid = threadIdx.x;
  int lane = tid & 63, w = tid >> 6;
  int el = lane & 15, g = lane >> 4;
  int r7 = el & 7;
  int m0 = blockIdx.x * 128, n0 = blockIdx.y * 128, z = blockIdx.z;
  const __hip_bfloat16* wz = wt + (size_t)z * F_ * E_;
  int wr = w >> 1, wc = w & 1;

  int srcoff = (((lane & 7) ^ ((lane >> 3) & 7)) << 3);
  auto stage = [&](int kk, int bf) {
#pragma unroll
    for (int i = 0; i < 4; i++) {
      gll16(xb + (size_t)(m0 + w * 32 + i * 8 + (lane >> 3)) * F_ + kk * 64 + srcoff,
            &Al[bf][w * 32 + i * 8][0]);
      gll16(wz + (size_t)(n0 + w * 32 + i * 8 + (lane >> 3)) * F_ + kk * 64 + srcoff,
            &Bl[bf][w * 32 + i * 8][0]);
    }
  };

  f32x4 acc[4][4] = {};
  stage(0, 0);
  asm volatile("s_waitcnt vmcnt(0)" ::: "memory");
  __syncthreads();

  for (int kk = 0; kk < 8; ++kk) {
    int bf = kk & 1;
    if (kk < 7) stage(kk + 1, bf ^ 1);
#pragma unroll
    for (int ks = 0; ks < 2; ++ks) {
      bf16x8 av[4], bv[4];
#pragma unroll
      for (int mi = 0; mi < 4; mi++)
        av[mi] = *(const bf16x8*)((const char*)&Al[bf][0][0] +
                                  (wr * 64 + mi * 16 + el) * 128 +
                                  (((ks * 4 + g) ^ r7) << 4));
#pragma unroll
      for (int ni = 0; ni < 4; ni++)
        bv[ni] = *(const bf16x8*)((const char*)&Bl[bf][0][0] +
                                  (wc * 64 + ni * 16 + el) * 128 +
                                  (((ks * 4 + g) ^ r7) << 4));
#pragma unroll
      for (int mi = 0; mi < 4; mi++)
#pragma unroll
        for (int ni = 0; ni < 4; ni++)
          acc[mi][ni] = mfma16(av[mi], bv[ni], acc[mi][ni]);
    }
    asm volatile("s_waitcnt vmcnt(0)" ::: "memory");
    __syncthreads();
  }

  float sc = (z == 0) ? QSCALE : 1.0f;
#pragma unroll
  for (int mi = 0; mi < 4; mi++)
#pragma unroll
    for (int ni = 0; ni < 4; ni++) {
      int mB = m0 + wr * 64 + mi * 16 + g * 4;
      int n = n0 + wc * 64 + ni * 16 + el;
      if (z == 2) {
        union { __hip_bfloat16 h[4]; uint2 u; } pk;
#pragma unroll
        for (int r = 0; r < 4; r++) pk.h[r] = __float2bfloat16(acc[mi][ni][r]);
        int b = mB >> 11, sl = mB & 2047;
        *(uint2*)&Vt[(size_t)b * E_ * S_ + (size_t)n * S_ + sl] = pk.u;
      } else {
#pragma unroll
        for (int r = 0; r < 4; r++) {
          __hip_bfloat16 v = __float2bfloat16(acc[mi][ni][r] * sc);
          if (z == 0) Qb[(size_t)(mB + r) * E_ + n] = v;
          else Kb[(size_t)(mB + r) * E_ + n] = v;
        }
      }
    }
}

// ---------------- kernel 1b: fp32 fallback GEMM (only if ws too small) -------
__global__ __launch_bounds__(256, 2) void qkv_kernel(
    const float* __restrict__ x, const __hip_bfloat16* __restrict__ wt,
    __hip_bfloat16* __restrict__ Qb, __hip_bfloat16* __restrict__ Kb,
    __hip_bfloat16* __restrict__ Vt) {
  __shared__ __hip_bfloat16 Al[2][128][72];
  __shared__ __hip_bfloat16 Bl[2][128][72];
  int tid = threadIdx.x;
  int lane = tid & 63, w = tid >> 6;
  int el = lane & 15, g = lane >> 4;
  int m0 = blockIdx.x * 128, n0 = blockIdx.y * 128, z = blockIdx.z;
  const __hip_bfloat16* wz = wt + (size_t)z * F_ * E_;
  int wr = w >> 1, wc = w & 1;
  float4 fa[8];
  uint4 vb[4];
  auto load = [&](int kk) {
#pragma unroll
    for (int c = 0; c < 4; c++) {
      int id = tid + 256 * c;
      int row = id >> 3, k8 = (id & 7) * 8;
      const float* s = x + (size_t)(m0 + row) * F_ + kk * 64 + k8;
      fa[2 * c] = *(const float4*)s;
      fa[2 * c + 1] = *(const float4*)(s + 4);
      vb[c] = *(const uint4*)(wz + (size_t)(n0 + row) * F_ + kk * 64 + k8);
    }
  };
  auto store_lds = [&](int bf) {
#pragma unroll
    for (int c = 0; c < 4; c++) {
      int id = tid + 256 * c;
      int row = id >> 3, k8 = (id & 7) * 8;
      union { __hip_bfloat16 h[8]; uint4 u; } cv;
      cv.h[0] = __float2bfloat16(fa[2 * c].x);
      cv.h[1] = __float2bfloat16(fa[2 * c].y);
      cv.h[2] = __float2bfloat16(fa[2 * c].z);
      cv.h[3] = __float2bfloat16(fa[2 * c].w);
      cv.h[4] = __float2bfloat16(fa[2 * c + 1].x);
      cv.h[5] = __float2bfloat16(fa[2 * c + 1].y);
      cv.h[6] = __float2bfloat16(fa[2 * c + 1].z);
      cv.h[7] = __float2bfloat16(fa[2 * c + 1].w);
      *(uint4*)&Al[bf][row][k8] = cv.u;
      *(uint4*)&Bl[bf][row][k8] = vb[c];
    }
  };
  f32x4 acc[4][4] = {};
  load(0);
  store_lds(0);
  __syncthreads();
  for (int kk = 0; kk < 8; ++kk) {
    int bf = kk & 1;
    if (kk < 7) load(kk + 1);
#pragma unroll
    for (int ks = 0; ks < 2; ++ks) {
      bf16x8 av[4], bv[4];
#pragma unroll
      for (int mi = 0; mi < 4; mi++)
        av[mi] = *(const bf16x8*)((const char*)&Al[bf][0][0] +
                                  (wr * 64 + mi * 16 + el) * 144 + (ks * 32 + g * 8) * 2);
#pragma unroll
      for (int ni = 0; ni < 4; ni++)
        bv[ni] = *(const bf16x8*)((const char*)&Bl[bf][0][0] +
                                  (wc * 64 + ni * 16 + el) * 144 + (ks * 32 + g * 8) * 2);
#pragma unroll
      for (int mi = 0; mi < 4; mi++)
#pragma unroll
        for (int ni = 0; ni < 4; ni++)
          acc[mi][ni] = mfma16(av[mi], bv[ni], acc[mi][ni]);
    }
    if (kk < 7) store_lds(bf ^ 1);
    __syncthreads();
  }
  float sc = (z == 0) ? QSCALE : 1.0f;
#pragma unroll
  for (int mi = 0; mi < 4; mi++)
#pragma unroll
    for (int ni = 0; ni < 4; ni++)
#pragma unroll
      for (int r = 0; r < 4; r++) {
        int m = m0 + wr * 64 + mi * 16 + g * 4 + r;
        int n = n0 + wc * 64 + ni * 16 + el;
        __hip_bfloat16 v = __float2bfloat16(acc[mi][ni][r] * sc);
        if (z == 0) Qb[(size_t)m * E_ + n] = v;
        else if (z == 1) Kb[(size_t)m * E_ + n] = v;
        else {
          int b = m >> 11, sl = m & 2047;
          Vt[(size_t)b * E_ * S_ + (size_t)n * S_ + sl] = v;
        }
      }
}

// ---------------- kernel 2: flash attention, 32q/wave register-blocked ------
// 4 waves x 32 q-rows = 128 q/block, 1 block/CU (141KB LDS), 1 wave/SIMD with
// 512-reg budget (__launch_bounds__(256,1)): o 2x32 f32x4 (AGPR) + qf 2x16.
// Every K-frag / V-frag LDS read now feeds TWO MFMAs (q-halves) -> per-tile
// LDS bytes ~halved vs R12. K/V double-buffered, stage at top, 1 barrier/tile.
// Softmax: fixed base m=12 (scores ~N(0,0.5); rescale branch is safety-only).
// MODE 1: 256 blocks (batch=bx&7 XCD-affine, qt=(bx>>3)&15, half=bx>>7),
//         32 tiles; bf16 raw partials + (l,m); merge combines.
// MODE 0: 128 blocks, full kv (64 tiles), normalized fp32 store (fallback).
template <int MODE>
__global__ __launch_bounds__(256, 1) void attn_kernel(
    const __hip_bfloat16* __restrict__ Qb, const __hip_bfloat16* __restrict__ Kb,
    const __hip_bfloat16* __restrict__ Vt, float* __restrict__ out,
    __hip_bfloat16* __restrict__ part0, __hip_bfloat16* __restrict__ part1,
    float* __restrict__ Ls, float* __restrict__ Ms) {
  __shared__ __hip_bfloat16 Kl[2][32][512] __attribute__((aligned(16)));  // chunk-XOR swz
  __shared__ __hip_bfloat16 Vl[2][512][32] __attribute__((aligned(16)));  // chunk-XOR swz
  __shared__ __hip_bfloat16 Pl[4][32][40] __attribute__((aligned(16)));   // [wave][q32][kv]

  int tid = threadIdx.x;
  int lane = tid & 63, w = tid >> 6;
  int el = lane & 15, g = lane >> 4, x7 = lane & 7;
  int bx = blockIdx.x;
  int batch = bx & 7;
  int qt = MODE ? ((bx >> 3) & 15) : (bx >> 3);
  int half = MODE ? (bx >> 7) : 0;
  int nt = MODE ? 32 : 64;
  int tbase = half * 32;
  int q0 = qt * 128 + w * 32;

  // Q fragments for both 16-row q-halves (whole 512-e contraction), pre-scaled
  bf16x8 qf0[16], qf1[16];
  {
    const __hip_bfloat16* qp0 = Qb + (size_t)(batch * S_ + q0 + el) * E_ + g * 8;
    const __hip_bfloat16* qp1 = qp0 + (size_t)16 * E_;
#pragma unroll
    for (int s = 0; s < 16; s++) {
      qf0[s] = *(const bf16x8*)(qp0 + 32 * s);
      qf1[s] = *(const bf16x8*)(qp1 + 32 * s);
    }
  }

  f32x4 o0[32] = {}, o1[32] = {};
  float m0r = 12.0f, l0r = 0.f, m1r = 12.0f, l1r = 0.f;

  const char* kbase_g = (const char*)(Kb + (size_t)batch * S_ * E_);
  const char* vbase_g = (const char*)(Vt + (size_t)batch * E_ * S_);
  // per-lane source offset for V staging: e = eb + (lane>>2); chunk c = (lane&3)^((lane>>3)&3)
  int vsrc_lane = (lane >> 2) * (S_ * 2) + 16 * ((lane & 3) ^ ((lane >> 3) & 3));

  // stage K/V tile t into buffer bf; 4 waves: 8 K-rows + 128 V-e-rows each
  auto stage = [&](int t, int bf) {
#pragma unroll
    for (int i = 0; i < 8; i++) {  // K: one 1KB row per instr, XOR by row&7==i
      int row = w * 8 + i;
      const char* src =
          kbase_g + ((size_t)(t * 32 + row) * 512 + 8 * (lane ^ i)) * 2;
      gll16(src, &Kl[bf][row][0]);
    }
#pragma unroll
    for (int i = 0; i < 8; i++) {  // V: 16 e-rows (64B each) per instr
      int eb = (w * 8 + i) * 16;
      const char* src = vbase_g + (size_t)eb * (S_ * 2) + vsrc_lane + t * 64;
      gll16(src, &Vl[bf][eb][0]);
    }
  };

  // K read bases: addr(f,s) = (16f+el)*1024 + (s>>1)*128 + ((4*(s&1)+g)^x7)*16
  int ka0 = el * 1024 + ((g ^ x7) << 4);
  int ka1 = el * 1024 + (((4 + g) ^ x7) << 4);
  // V read base: addr(ni) = ni*1024 + el*64 + ((g ^ ((el>>1)&3))<<4)
  int vbase_l = el * 64 + ((g ^ ((el >> 1) & 3)) << 4);

  stage(tbase, 0);
  asm volatile("s_waitcnt vmcnt(0)" ::: "memory");
  __syncthreads();

  for (int i = 0; i < nt; ++i) {
    int bf = i & 1;
    // 1. prefetch tile i+1 into idle buffer (lands during this tile's compute)
    if (i + 1 < nt) stage(tbase + i + 1, bf ^ 1);
    // 2. QK^T both q-halves: each K-frag feeds 2 MFMAs
    const char* kl = (const char*)&Kl[bf][0][0];
    f32x4 st0[2] = {}, st1[2] = {};
    __builtin_amdgcn_s_setprio(1);
#pragma unroll
    for (int s = 0; s < 16; s++) {
      int base = ((s & 1) ? ka1 : ka0) + (s >> 1) * 128;
#pragma unroll
      for (int f = 0; f < 2; f++) {
        bf16x8 kf = *(const bf16x8*)(kl + base + f * 16384);
        st0[f] = mfma16(kf, qf0[s], st0[f]);
        st1[f] = mfma16(kf, qf1[s], st1[f]);
      }
    }
    __builtin_amdgcn_s_setprio(0);
    // 3. softmax, fixed base m=12 (safety rescale ~never fires)
    float vmax0 = st0[0][0], vmax1 = st1[0][0];
#pragma unroll
    for (int r = 1; r < 4; r++) {
      vmax0 = fmaxf(vmax0, st0[0][r]);
      vmax1 = fmaxf(vmax1, st1[0][r]);
    }
#pragma unroll
    for (int r = 0; r < 4; r++) {
      vmax0 = fmaxf(vmax0, st0[1][r]);
      vmax1 = fmaxf(vmax1, st1[1][r]);
    }
    vmax0 = fmaxf(vmax0, __shfl_xor(vmax0, 16));
    vmax0 = fmaxf(vmax0, __shfl_xor(vmax0, 32));
    vmax1 = fmaxf(vmax1, __shfl_xor(vmax1, 16));
    vmax1 = fmaxf(vmax1, __shfl_xor(vmax1, 32));
    if (__any(vmax0 > m0r)) {  // safety only
      float m_new = vmax0 + 4.0f;
      float fac = exp2f(m0r - m_new);
      float fo[4];
#pragma unroll
      for (int r = 0; r < 4; r++) fo[r] = __shfl(fac, g * 4 + r);
#pragma unroll
      for (int ni = 0; ni < 32; ni++) {
        o0[ni][0] *= fo[0]; o0[ni][1] *= fo[1]; o0[ni][2] *= fo[2]; o0[ni][3] *= fo[3];
      }
      l0r *= fac;
      m0r = m_new;
    }
    if (__any(vmax1 > m1r)) {
      float m_new = vmax1 + 4.0f;
      float fac = exp2f(m1r - m_new);
      float fo[4];
#pragma unroll
      for (int r = 0; r < 4; r++) fo[r] = __shfl(fac, g * 4 + r);
#pragma unroll
      for (int ni = 0; ni < 32; ni++) {
        o1[ni][0] *= fo[0]; o1[ni][1] *= fo[1]; o1[ni][2] *= fo[2]; o1[ni][3] *= fo[3];
      }
      l1r *= fac;
      m1r = m_new;
    }
    float rs0 = 0.f, rs1 = 0.f;
    float p0[8], p1[8];
#pragma unroll
    for (int f = 0; f < 2; f++)
#pragma unroll
      for (int r = 0; r < 4; r++) {
        float e0 = exp2f(st0[f][r] - m0r);
        float e1 = exp2f(st1[f][r] - m1r);
        p0[4 * f + r] = e0;
        p1[4 * f + r] = e1;
        rs0 += e0;
        rs1 += e1;
      }
    rs0 += __shfl_xor(rs0, 16);
    rs0 += __shfl_xor(rs0, 32);
    rs1 += __shfl_xor(rs1, 16);
    rs1 += __shfl_xor(rs1, 32);
    l0r += rs0;
    l1r += rs1;
    // 4. P -> bf16 -> per-wave LDS [q32][kv] (rows el and 16+el)
#pragma unroll
    for (int f = 0; f < 2; f++) {
      union { __hip_bfloat16 h[4]; uint2 u; } pk0, pk1;
#pragma unroll
      for (int r = 0; r < 4; r++) {
        pk0.h[r] = __float2bfloat16(p0[4 * f + r]);
        pk1.h[r] = __float2bfloat16(p1[4 * f + r]);
      }
      *(uint2*)((char*)&Pl[w][0][0] + el * 80 + 32 * f + 8 * g) = pk0.u;
      *(uint2*)((char*)&Pl[w][0][0] + (16 + el) * 80 + 32 * f + 8 * g) = pk1.u;
    }
    asm volatile("s_waitcnt lgkmcnt(0)" ::: "memory");
    bf16x8 pa0 = *(const bf16x8*)((const char*)&Pl[w][0][0] + el * 80 + g * 16);
    bf16x8 pa1 = *(const bf16x8*)((const char*)&Pl[w][0][0] + (16 + el) * 80 + g * 16);
    // 5. PV both q-halves: each V-frag feeds 2 MFMAs
    const char* vl = (const char*)&Vl[bf][0][0];
    __builtin_amdgcn_s_setprio(1);
#pragma unroll
    for (int ni = 0; ni < 32; ni++) {
      bf16x8 vf = *(const bf16x8*)(vl + vbase_l + ni * 1024);
      o0[ni] = mfma16(pa0, vf, o0[ni]);
      o1[ni] = mfma16(pa1, vf, o1[ni]);
    }
    __builtin_amdgcn_s_setprio(0);
    // 6. drain own DMAs (issued a full compute-phase ago -> ~free), flip
    asm volatile("s_waitcnt vmcnt(0)" ::: "memory");
    __syncthreads();
  }

  if (MODE == 0) {
    float li0[4], li1[4];
#pragma unroll
    for (int r = 0; r < 4; r++) {
      li0[r] = 1.0f / __shfl(l0r, g * 4 + r);
      li1[r] = 1.0f / __shfl(l1r, g * 4 + r);
    }
    float* ob0 = out + (size_t)(batch * S_ + q0 + g * 4) * E_ + el;
    float* ob1 = ob0 + (size_t)16 * E_;
#pragma unroll
    for (int ni = 0; ni < 32; ni++)
#pragma unroll
      for (int r = 0; r < 4; r++) {
        ob0[(size_t)r * E_ + ni * 16] = o0[ni][r] * li0[r];
        ob1[(size_t)r * E_ + ni * 16] = o1[ni][r] * li1[r];
      }
  } else {
    __hip_bfloat16* dst = (half == 0) ? part0 : part1;
    __hip_bfloat16* ob0 = dst + (size_t)(batch * S_ + q0 + g * 4) * E_ + el;
    __hip_bfloat16* ob1 = ob0 + (size_t)16 * E_;
#pragma unroll
    for (int ni = 0; ni < 32; ni++)
#pragma unroll
      for (int r = 0; r < 4; r++) {
        ob0[(size_t)r * E_ + ni * 16] = __float2bfloat16(o0[ni][r]);
        ob1[(size_t)r * E_ + ni * 16] = __float2bfloat16(o1[ni][r]);
      }
    if (g == 0) {
      int idx = half * (B_ * S_) + batch * S_ + q0 + el;
      Ls[idx] = l0r;
      Ms[idx] = m0r;
      Ls[idx + 16] = l1r;
      Ms[idx + 16] = m1r;
    }
  }
}

// ---------------- kernel 3: combine kv-split partials (bf16 in, fp32 out) ----
// out = (O0*w0 + O1*w1) / (l0*w0 + l1*w1), w_i = exp2(m_i - max(m0,m1))
__global__ void merge_kernel(float* __restrict__ out,
                             const __hip_bfloat16* __restrict__ p0,
                             const __hip_bfloat16* __restrict__ p1,
                             const float* __restrict__ Ls,
                             const float* __restrict__ Ms) {
  int idx = blockIdx.x * 256 + threadIdx.x;  // 8 elems per thread
  int row = idx >> 6;                        // E/8 = 64 chunks per row
  int c8 = (idx & 63) * 8;
  float l0 = Ls[row], m0 = Ms[row];
  float l1 = Ls[B_ * S_ + row], m1 = Ms[B_ * S_ + row];
  float m = fmaxf(m0, m1);
  float w0 = exp2f(m0 - m), w1 = exp2f(m1 - m);
  float inv = 1.0f / (l0 * w0 + l1 * w1);
  size_t off = (size_t)row * E_ + c8;
  union { uint4 u; ushort h[8]; } ua, ub;
  ua.u = *(const uint4*)(p0 + off);
  ub.u = *(const uint4*)(p1 + off);
  float r[8];
#pragma unroll
  for (int j = 0; j < 8; j++) {
    union { uint32_t u; float f; } a, b;
    a.u = (uint32_t)ua.h[j] << 16;
    b.u = (uint32_t)ub.h[j] << 16;
    r[j] = (a.f * w0 + b.f * w1) * inv;
  }
  *(float4*)(out + off) = *(float4*)&r[0];
  *(float4*)(out + off + 4) = *(float4*)&r[4];
}

// ---------------- launch ----------------
extern "C" void kernel_launch(void* const* d_in, const int* in_sizes, int n_in,
                              void* d_out, int out_size, void* d_ws, size_t ws_size,
                              hipStream_t stream) {
  const float* x = (const float*)d_in[0];
  const float* wq = (const float*)d_in[1];
  const float* wk = (const float*)d_in[2];
  const float* wv = (const float*)d_in[3];
  float* out = (float*)d_out;

  char* ws = (char*)d_ws;
  __hip_bfloat16* wt = (__hip_bfloat16*)ws;                          // 1.5 MB
  __hip_bfloat16* Qb = (__hip_bfloat16*)(ws + (size_t)3 * F_ * E_ * 2);
  __hip_bfloat16* Kb = Qb + (size_t)B_ * S_ * E_;
  __hip_bfloat16* Vt = Kb + (size_t)B_ * S_ * E_;
  __hip_bfloat16* xb = Vt + (size_t)B_ * S_ * E_;                    // +16 MB (=65.5)
  __hip_bfloat16* part0 = xb + (size_t)B_ * S_ * F_;                 // +16 MB
  __hip_bfloat16* part1 = part0 + (size_t)B_ * S_ * E_;              // +16 MB
  float* Ls = (float*)(part1 + (size_t)B_ * S_ * E_);                // 2*16384 f32
  float* Ms = Ls + 2 * B_ * S_;

  size_t need_bfx = (size_t)3 * F_ * E_ * 2 + (size_t)3 * B_ * S_ * E_ * 2 +
                    (size_t)B_ * S_ * F_ * 2;                        // 65.5 MB
  size_t need_split = need_bfx + (size_t)2 * B_ * S_ * E_ * 2 + 4 * B_ * S_ * 4;  // ~98 MB
  bool bfx = (ws_size >= need_bfx);
  bool split = (ws_size >= need_split);

  dim3 b0(32, 8), g0(16, 16, 3);
  wtrans_kernel<<<g0, b0, 0, stream>>>(wq, wk, wv, wt);

  dim3 g1(128, 4, 3);
  if (bfx) {
    xconv_kernel<<<(B_ * S_ * F_) / (256 * 8), 256, 0, stream>>>(x, xb);
    qkvg_kernel<<<g1, 256, 0, stream>>>(xb, wt, Qb, Kb, Vt);
  } else {
    qkv_kernel<<<g1, 256, 0, stream>>>(x, wt, Qb, Kb, Vt);
  }

  if (split) {
    attn_kernel<1><<<256, 256, 0, stream>>>(Qb, Kb, Vt, out, part0, part1, Ls, Ms);
    merge_kernel<<<(B_ * S_ * E_ / 8) / 256, 256, 0, stream>>>(out, part0, part1, Ls, Ms);
  } else {
    attn_kernel<0><<<128, 256, 0, stream>>>(Qb, Kb, Vt, out, nullptr, nullptr,
                                            nullptr, nullptr);
  }
}

// Round 14
// 175.548 us; speedup vs baseline: 2.9382x; 2.9382x over previous
//
#include <hip/hip_runtime.h>
#include <hip/hip_bf16.h>
#include <stdint.h>

#define B_ 8
#define S_ 2048
#define F_ 512
#define E_ 512

typedef short bf16x8 __attribute__((ext_vector_type(8)));
typedef float f32x4 __attribute__((ext_vector_type(4)));

__device__ __forceinline__ f32x4 mfma16(bf16x8 a, bf16x8 b, f32x4 c) {
  return __builtin_amdgcn_mfma_f32_16x16x32_bf16(a, b, c, 0, 0, 0);
}

// async global->LDS, 16B per lane; dst is wave-uniform base, src per-lane
__device__ __forceinline__ void gll16(const void* g, void* l) {
  __builtin_amdgcn_global_load_lds(
      (const __attribute__((address_space(1))) void*)g,
      (__attribute__((address_space(3))) void*)l, 16, 0, 0);
}

// softmax scale folded into Q at projection time: log2(e)/sqrt(E)
constexpr float QSCALE = 0.0441941738f * 1.44269504f;

// ---------------- kernel A: x fp32 -> bf16 ----------------
__global__ void xconv_kernel(const float* __restrict__ x,
                             __hip_bfloat16* __restrict__ xb) {
  int i = (blockIdx.x * 256 + threadIdx.x) * 8;
  float4 a = *(const float4*)(x + i);
  float4 b = *(const float4*)(x + i + 4);
  union { __hip_bfloat16 h[8]; uint4 u; } cv;
  cv.h[0] = __float2bfloat16(a.x);
  cv.h[1] = __float2bfloat16(a.y);
  cv.h[2] = __float2bfloat16(a.z);
  cv.h[3] = __float2bfloat16(a.w);
  cv.h[4] = __float2bfloat16(b.x);
  cv.h[5] = __float2bfloat16(b.y);
  cv.h[6] = __float2bfloat16(b.z);
  cv.h[7] = __float2bfloat16(b.w);
  *(uint4*)(xb + i) = cv.u;
}

// ---------------- kernel 0: W[f][e] fp32 -> Wt[e][f] bf16 (x3) ----------------
__global__ void wtrans_kernel(const float* __restrict__ wq,
                              const float* __restrict__ wk,
                              const float* __restrict__ wv,
                              __hip_bfloat16* __restrict__ wt) {
  __shared__ float t[32][33];
  const float* w = (blockIdx.z == 0) ? wq : (blockIdx.z == 1 ? wk : wv);
  __hip_bfloat16* o = wt + (size_t)blockIdx.z * F_ * E_;
  int e0 = blockIdx.x * 32, f0 = blockIdx.y * 32;
  int tx = threadIdx.x, ty = threadIdx.y;
#pragma unroll
  for (int i = 0; i < 4; i++)
    t[ty + 8 * i][tx] = w[(size_t)(f0 + ty + 8 * i) * E_ + e0 + tx];
  __syncthreads();
#pragma unroll
  for (int i = 0; i < 4; i++)
    o[(size_t)(e0 + ty + 8 * i) * F_ + f0 + tx] = __float2bfloat16(t[tx][ty + 8 * i]);
}

// ---------------- kernel 1: QKV projection GEMM, gll16-staged ----------------
__global__ __launch_bounds__(256, 2) void qkvg_kernel(
    const __hip_bfloat16* __restrict__ xb, const __hip_bfloat16* __restrict__ wt,
    __hip_bfloat16* __restrict__ Qb, __hip_bfloat16* __restrict__ Kb,
    __hip_bfloat16* __restrict__ Vt) {
  __shared__ __hip_bfloat16 Al[2][128][64] __attribute__((aligned(16)));
  __shared__ __hip_bfloat16 Bl[2][128][64] __attribute__((aligned(16)));

  int tid = threadIdx.x;
  int lane = tid & 63, w = tid >> 6;
  int el = lane & 15, g = lane >> 4;
  int r7 = el & 7;
  int m0 = blockIdx.x * 128, n0 = blockIdx.y * 128, z = blockIdx.z;
  const __hip_bfloat16* wz = wt + (size_t)z * F_ * E_;
  int wr = w >> 1, wc = w & 1;

  int srcoff = (((lane & 7) ^ ((lane >> 3) & 7)) << 3);
  auto stage = [&](int kk, int bf) {
#pragma unroll
    for (int i = 0; i < 4; i++) {
      gll16(xb + (size_t)(m0 + w * 32 + i * 8 + (lane >> 3)) * F_ + kk * 64 + srcoff,
            &Al[bf][w * 32 + i * 8][0]);
      gll16(wz + (size_t)(n0 + w * 32 + i * 8 + (lane >> 3)) * F_ + kk * 64 + srcoff,
            &Bl[bf][w * 32 + i * 8][0]);
    }
  };

  f32x4 acc[4][4] = {};
  stage(0, 0);
  asm volatile("s_waitcnt vmcnt(0)" ::: "memory");
  __syncthreads();

  for (int kk = 0; kk < 8; ++kk) {
    int bf = kk & 1;
    if (kk < 7) stage(kk + 1, bf ^ 1);
#pragma unroll
    for (int ks = 0; ks < 2; ++ks) {
      bf16x8 av[4], bv[4];
#pragma unroll
      for (int mi = 0; mi < 4; mi++)
        av[mi] = *(const bf16x8*)((const char*)&Al[bf][0][0] +
                                  (wr * 64 + mi * 16 + el) * 128 +
                                  (((ks * 4 + g) ^ r7) << 4));
#pragma unroll
      for (int ni = 0; ni < 4; ni++)
        bv[ni] = *(const bf16x8*)((const char*)&Bl[bf][0][0] +
                                  (wc * 64 + ni * 16 + el) * 128 +
                                  (((ks * 4 + g) ^ r7) << 4));
#pragma unroll
      for (int mi = 0; mi < 4; mi++)
#pragma unroll
        for (int ni = 0; ni < 4; ni++)
          acc[mi][ni] = mfma16(av[mi], bv[ni], acc[mi][ni]);
    }
    asm volatile("s_waitcnt vmcnt(0)" ::: "memory");
    __syncthreads();
  }

  float sc = (z == 0) ? QSCALE : 1.0f;
#pragma unroll
  for (int mi = 0; mi < 4; mi++)
#pragma unroll
    for (int ni = 0; ni < 4; ni++) {
      int mB = m0 + wr * 64 + mi * 16 + g * 4;
      int n = n0 + wc * 64 + ni * 16 + el;
      if (z == 2) {
        union { __hip_bfloat16 h[4]; uint2 u; } pk;
#pragma unroll
        for (int r = 0; r < 4; r++) pk.h[r] = __float2bfloat16(acc[mi][ni][r]);
        int b = mB >> 11, sl = mB & 2047;
        *(uint2*)&Vt[(size_t)b * E_ * S_ + (size_t)n * S_ + sl] = pk.u;
      } else {
#pragma unroll
        for (int r = 0; r < 4; r++) {
          __hip_bfloat16 v = __float2bfloat16(acc[mi][ni][r] * sc);
          if (z == 0) Qb[(size_t)(mB + r) * E_ + n] = v;
          else Kb[(size_t)(mB + r) * E_ + n] = v;
        }
      }
    }
}

// ---------------- kernel 1b: fp32 fallback GEMM (only if ws too small) -------
__global__ __launch_bounds__(256, 2) void qkv_kernel(
    const float* __restrict__ x, const __hip_bfloat16* __restrict__ wt,
    __hip_bfloat16* __restrict__ Qb, __hip_bfloat16* __restrict__ Kb,
    __hip_bfloat16* __restrict__ Vt) {
  __shared__ __hip_bfloat16 Al[2][128][72];
  __shared__ __hip_bfloat16 Bl[2][128][72];
  int tid = threadIdx.x;
  int lane = tid & 63, w = tid >> 6;
  int el = lane & 15, g = lane >> 4;
  int m0 = blockIdx.x * 128, n0 = blockIdx.y * 128, z = blockIdx.z;
  const __hip_bfloat16* wz = wt + (size_t)z * F_ * E_;
  int wr = w >> 1, wc = w & 1;
  float4 fa[8];
  uint4 vb[4];
  auto load = [&](int kk) {
#pragma unroll
    for (int c = 0; c < 4; c++) {
      int id = tid + 256 * c;
      int row = id >> 3, k8 = (id & 7) * 8;
      const float* s = x + (size_t)(m0 + row) * F_ + kk * 64 + k8;
      fa[2 * c] = *(const float4*)s;
      fa[2 * c + 1] = *(const float4*)(s + 4);
      vb[c] = *(const uint4*)(wz + (size_t)(n0 + row) * F_ + kk * 64 + k8);
    }
  };
  auto store_lds = [&](int bf) {
#pragma unroll
    for (int c = 0; c < 4; c++) {
      int id = tid + 256 * c;
      int row = id >> 3, k8 = (id & 7) * 8;
      union { __hip_bfloat16 h[8]; uint4 u; } cv;
      cv.h[0] = __float2bfloat16(fa[2 * c].x);
      cv.h[1] = __float2bfloat16(fa[2 * c].y);
      cv.h[2] = __float2bfloat16(fa[2 * c].z);
      cv.h[3] = __float2bfloat16(fa[2 * c].w);
      cv.h[4] = __float2bfloat16(fa[2 * c + 1].x);
      cv.h[5] = __float2bfloat16(fa[2 * c + 1].y);
      cv.h[6] = __float2bfloat16(fa[2 * c + 1].z);
      cv.h[7] = __float2bfloat16(fa[2 * c + 1].w);
      *(uint4*)&Al[bf][row][k8] = cv.u;
      *(uint4*)&Bl[bf][row][k8] = vb[c];
    }
  };
  f32x4 acc[4][4] = {};
  load(0);
  store_lds(0);
  __syncthreads();
  for (int kk = 0; kk < 8; ++kk) {
    int bf = kk & 1;
    if (kk < 7) load(kk + 1);
#pragma unroll
    for (int ks = 0; ks < 2; ++ks) {
      bf16x8 av[4], bv[4];
#pragma unroll
      for (int mi = 0; mi < 4; mi++)
        av[mi] = *(const bf16x8*)((const char*)&Al[bf][0][0] +
                                  (wr * 64 + mi * 16 + el) * 144 + (ks * 32 + g * 8) * 2);
#pragma unroll
      for (int ni = 0; ni < 4; ni++)
        bv[ni] = *(const bf16x8*)((const char*)&Bl[bf][0][0] +
                                  (wc * 64 + ni * 16 + el) * 144 + (ks * 32 + g * 8) * 2);
#pragma unroll
      for (int mi = 0; mi < 4; mi++)
#pragma unroll
        for (int ni = 0; ni < 4; ni++)
          acc[mi][ni] = mfma16(av[mi], bv[ni], acc[mi][ni]);
    }
    if (kk < 7) store_lds(bf ^ 1);
    __syncthreads();
  }
  float sc = (z == 0) ? QSCALE : 1.0f;
#pragma unroll
  for (int mi = 0; mi < 4; mi++)
#pragma unroll
    for (int ni = 0; ni < 4; ni++)
#pragma unroll
      for (int r = 0; r < 4; r++) {
        int m = m0 + wr * 64 + mi * 16 + g * 4 + r;
        int n = n0 + wc * 64 + ni * 16 + el;
        __hip_bfloat16 v = __float2bfloat16(acc[mi][ni][r] * sc);
        if (z == 0) Qb[(size_t)m * E_ + n] = v;
        else if (z == 1) Kb[(size_t)m * E_ + n] = v;
        else {
          int b = m >> 11, sl = m & 2047;
          Vt[(size_t)b * E_ * S_ + (size_t)n * S_ + sl] = v;
        }
      }
}

// ---------------- kernel 2: flash attention, 8-wave block + K/V dbuf --------
// (R12-proven best: one 512-thread block per CU, LDS 138KB, q-tile 128,
//  KVT=32 double-buffered, stage(t+1) at top of compute(t), 1 barrier/tile.)
// MODE 1: 256 blocks (batch=bx&7 XCD-affine, qt=(bx>>3)&15, half=bx>>7),
//         32 tiles; bf16 raw partials + (l,m); merge combines.
// MODE 0: 128 blocks, full kv (64 tiles), normalized fp32 store (fallback).
template <int MODE>
__global__ __launch_bounds__(512, 2) void attn_kernel(
    const __hip_bfloat16* __restrict__ Qb, const __hip_bfloat16* __restrict__ Kb,
    const __hip_bfloat16* __restrict__ Vt, float* __restrict__ out,
    __hip_bfloat16* __restrict__ part0, __hip_bfloat16* __restrict__ part1,
    float* __restrict__ Ls, float* __restrict__ Ms) {
  __shared__ __hip_bfloat16 Kl[2][32][512] __attribute__((aligned(16)));  // chunk-XOR swz
  __shared__ __hip_bfloat16 Vl[2][512][32] __attribute__((aligned(16)));  // chunk-XOR swz
  __shared__ __hip_bfloat16 Pl[8][16][40] __attribute__((aligned(16)));

  int tid = threadIdx.x;
  int lane = tid & 63, w = tid >> 6;
  int el = lane & 15, g = lane >> 4, x7 = lane & 7;
  int bx = blockIdx.x;
  int batch = bx & 7;
  int qt = MODE ? ((bx >> 3) & 15) : (bx >> 3);
  int half = MODE ? (bx >> 7) : 0;
  int nt = MODE ? 32 : 64;
  int tbase = half * 32;
  int q0 = qt * 128 + w * 16;

  // Q fragments in registers (whole 512-e contraction), pre-scaled in ws
  bf16x8 qf[16];
  {
    const __hip_bfloat16* qptr = Qb + (size_t)(batch * S_ + q0 + el) * E_ + g * 8;
#pragma unroll
    for (int s = 0; s < 16; s++) qf[s] = *(const bf16x8*)(qptr + 32 * s);
  }

  f32x4 o[32] = {};
  float m_run = -INFINITY, l_run = 0.f;

  const char* kbase_g = (const char*)(Kb + (size_t)batch * S_ * E_);
  const char* vbase_g = (const char*)(Vt + (size_t)batch * E_ * S_);
  // per-lane source offset for V staging: e = eb + (lane>>2); chunk c = (lane&3)^((lane>>3)&3)
  int vsrc_lane = (lane >> 2) * (S_ * 2) + 16 * ((lane & 3) ^ ((lane >> 3) & 3));

  // stage K/V tile t into buffer bf; 8 waves: 4 K-rows + 64 V-e-rows each
  auto stage = [&](int t, int bf) {
#pragma unroll
    for (int i = 0; i < 4; i++) {  // K: one 1KB row per instr, XOR by row&7
      int row = w * 4 + i;
      const char* src =
          kbase_g + ((size_t)(t * 32 + row) * 512 + 8 * (lane ^ (row & 7))) * 2;
      gll16(src, &Kl[bf][row][0]);
    }
#pragma unroll
    for (int i = 0; i < 4; i++) {  // V: 16 e-rows (64B each) per instr
      int eb = (w * 4 + i) * 16;
      const char* src = vbase_g + (size_t)eb * (S_ * 2) + vsrc_lane + t * 64;
      gll16(src, &Vl[bf][eb][0]);
    }
  };

  // K read bases: addr(f,s) = (16f+el)*1024 + (s>>1)*128 + ((4*(s&1)+g)^x7)*16
  int ka0 = el * 1024 + ((g ^ x7) << 4);
  int ka1 = el * 1024 + (((4 + g) ^ x7) << 4);
  // V read base: addr(ni) = ni*1024 + el*64 + ((g ^ ((el>>1)&3))<<4)
  int vbase_l = el * 64 + ((g ^ ((el >> 1) & 3)) << 4);

  stage(tbase, 0);
  asm volatile("s_waitcnt vmcnt(0)" ::: "memory");
  __syncthreads();

  for (int i = 0; i < nt; ++i) {
    int bf = i & 1;
    // 1. prefetch tile i+1 into idle buffer (lands during this tile's compute)
    if (i + 1 < nt) stage(tbase + i + 1, bf ^ 1);
    // 2. QK^T: st = K·Q -> lane holds S^T[kv=16f+4g+r][q=el]
    const char* kl = (const char*)&Kl[bf][0][0];
    f32x4 st[2] = {};
    __builtin_amdgcn_s_setprio(1);
#pragma unroll
    for (int s = 0; s < 16; s++) {
      int base = ((s & 1) ? ka1 : ka0) + (s >> 1) * 128;
#pragma unroll
      for (int f = 0; f < 2; f++) {
        bf16x8 kf = *(const bf16x8*)(kl + base + f * 16384);
        st[f] = mfma16(kf, qf[s], st[f]);
      }
    }
    __builtin_amdgcn_s_setprio(0);
    // 3. online softmax (exp2 space; scale pre-folded into Q), defer-max THR=8
    float vmax = st[0][0];
#pragma unroll
    for (int r = 1; r < 4; r++) vmax = fmaxf(vmax, st[0][r]);
#pragma unroll
    for (int r = 0; r < 4; r++) vmax = fmaxf(vmax, st[1][r]);
    vmax = fmaxf(vmax, __shfl_xor(vmax, 16));
    vmax = fmaxf(vmax, __shfl_xor(vmax, 32));
    if (__any(vmax > m_run + 8.0f)) {
      float m_new = fmaxf(m_run, vmax);
      float fac = exp2f(m_run - m_new);
      float fo[4];
#pragma unroll
      for (int r = 0; r < 4; r++) fo[r] = __shfl(fac, g * 4 + r);
#pragma unroll
      for (int ni = 0; ni < 32; ni++) {
        o[ni][0] *= fo[0]; o[ni][1] *= fo[1]; o[ni][2] *= fo[2]; o[ni][3] *= fo[3];
      }
      l_run *= fac;
      m_run = m_new;
    }
    float p[8];
    float rs = 0.f;
#pragma unroll
    for (int f = 0; f < 2; f++)
#pragma unroll
      for (int r = 0; r < 4; r++) {
        float e2 = exp2f(st[f][r] - m_run);
        p[4 * f + r] = e2;
        rs += e2;
      }
    rs += __shfl_xor(rs, 16);
    rs += __shfl_xor(rs, 32);
    l_run += rs;
    // 4. P -> bf16 -> per-wave LDS [q][kv] -> A-fragment
#pragma unroll
    for (int f = 0; f < 2; f++) {
      union { __hip_bfloat16 h[4]; uint2 u; } pk;
      pk.h[0] = __float2bfloat16(p[4 * f + 0]);
      pk.h[1] = __float2bfloat16(p[4 * f + 1]);
      pk.h[2] = __float2bfloat16(p[4 * f + 2]);
      pk.h[3] = __float2bfloat16(p[4 * f + 3]);
      *(uint2*)((char*)&Pl[w][0][0] + el * 80 + 32 * f + 8 * g) = pk.u;
    }
    asm volatile("s_waitcnt lgkmcnt(0)" ::: "memory");
    bf16x8 pa = *(const bf16x8*)((const char*)&Pl[w][0][0] + el * 80 + g * 16);
    // 5. PV: O += P · V
    const char* vl = (const char*)&Vl[bf][0][0];
    __builtin_amdgcn_s_setprio(1);
#pragma unroll
    for (int ni = 0; ni < 32; ni++) {
      bf16x8 vf = *(const bf16x8*)(vl + vbase_l + ni * 1024);
      o[ni] = mfma16(pa, vf, o[ni]);
    }
    __builtin_amdgcn_s_setprio(0);
    // 6. drain own DMAs (issued a full compute-phase ago -> ~free), flip
    asm volatile("s_waitcnt vmcnt(0)" ::: "memory");
    __syncthreads();
  }

  if (MODE == 0) {
    // normalize by l and store fp32
    float linv[4];
#pragma unroll
    for (int r = 0; r < 4; r++) {
      float lr = __shfl(l_run, g * 4 + r);
      linv[r] = 1.0f / lr;
    }
    float* ob = out + (size_t)(batch * S_ + q0 + g * 4) * E_ + el;
#pragma unroll
    for (int ni = 0; ni < 32; ni++)
#pragma unroll
      for (int r = 0; r < 4; r++)
        ob[(size_t)r * E_ + ni * 16] = o[ni][r] * linv[r];
  } else {
    // raw bf16 partial store; half0 -> part0, half1 -> part1
    __hip_bfloat16* dst = (half == 0) ? part0 : part1;
    __hip_bfloat16* ob = dst + (size_t)(batch * S_ + q0 + g * 4) * E_ + el;
#pragma unroll
    for (int ni = 0; ni < 32; ni++)
#pragma unroll
      for (int r = 0; r < 4; r++)
        ob[(size_t)r * E_ + ni * 16] = __float2bfloat16(o[ni][r]);
    if (g == 0) {
      int idx = half * (B_ * S_) + batch * S_ + q0 + el;
      Ls[idx] = l_run;
      Ms[idx] = m_run;
    }
  }
}

// ---------------- kernel 3: combine kv-split partials (bf16 in, fp32 out) ----
// out = (O0*w0 + O1*w1) / (l0*w0 + l1*w1), w_i = exp2(m_i - max(m0,m1))
__global__ void merge_kernel(float* __restrict__ out,
                             const __hip_bfloat16* __restrict__ p0,
                             const __hip_bfloat16* __restrict__ p1,
                             const float* __restrict__ Ls,
                             const float* __restrict__ Ms) {
  int idx = blockIdx.x * 256 + threadIdx.x;  // 8 elems per thread
  int row = idx >> 6;                        // E/8 = 64 chunks per row
  int c8 = (idx & 63) * 8;
  float l0 = Ls[row], m0 = Ms[row];
  float l1 = Ls[B_ * S_ + row], m1 = Ms[B_ * S_ + row];
  float m = fmaxf(m0, m1);
  float w0 = exp2f(m0 - m), w1 = exp2f(m1 - m);
  float inv = 1.0f / (l0 * w0 + l1 * w1);
  size_t off = (size_t)row * E_ + c8;
  union { uint4 u; ushort h[8]; } ua, ub;
  ua.u = *(const uint4*)(p0 + off);
  ub.u = *(const uint4*)(p1 + off);
  float r[8];
#pragma unroll
  for (int j = 0; j < 8; j++) {
    union { uint32_t u; float f; } a, b;
    a.u = (uint32_t)ua.h[j] << 16;
    b.u = (uint32_t)ub.h[j] << 16;
    r[j] = (a.f * w0 + b.f * w1) * inv;
  }
  *(float4*)(out + off) = *(float4*)&r[0];
  *(float4*)(out + off + 4) = *(float4*)&r[4];
}

// ---------------- launch ----------------
extern "C" void kernel_launch(void* const* d_in, const int* in_sizes, int n_in,
                              void* d_out, int out_size, void* d_ws, size_t ws_size,
                              hipStream_t stream) {
  const float* x = (const float*)d_in[0];
  const float* wq = (const float*)d_in[1];
  const float* wk = (const float*)d_in[2];
  const float* wv = (const float*)d_in[3];
  float* out = (float*)d_out;

  char* ws = (char*)d_ws;
  __hip_bfloat16* wt = (__hip_bfloat16*)ws;                          // 1.5 MB
  __hip_bfloat16* Qb = (__hip_bfloat16*)(ws + (size_t)3 * F_ * E_ * 2);
  __hip_bfloat16* Kb = Qb + (size_t)B_ * S_ * E_;
  __hip_bfloat16* Vt = Kb + (size_t)B_ * S_ * E_;
  __hip_bfloat16* xb = Vt + (size_t)B_ * S_ * E_;                    // +16 MB (=65.5)
  __hip_bfloat16* part0 = xb + (size_t)B_ * S_ * F_;                 // +16 MB
  __hip_bfloat16* part1 = part0 + (size_t)B_ * S_ * E_;              // +16 MB
  float* Ls = (float*)(part1 + (size_t)B_ * S_ * E_);                // 2*16384 f32
  float* Ms = Ls + 2 * B_ * S_;

  size_t need_bfx = (size_t)3 * F_ * E_ * 2 + (size_t)3 * B_ * S_ * E_ * 2 +
                    (size_t)B_ * S_ * F_ * 2;                        // 65.5 MB
  size_t need_split = need_bfx + (size_t)2 * B_ * S_ * E_ * 2 + 4 * B_ * S_ * 4;  // ~98 MB
  bool bfx = (ws_size >= need_bfx);
  bool split = (ws_size >= need_split);

  dim3 b0(32, 8), g0(16, 16, 3);
  wtrans_kernel<<<g0, b0, 0, stream>>>(wq, wk, wv, wt);

  dim3 g1(128, 4, 3);
  if (bfx) {
    xconv_kernel<<<(B_ * S_ * F_) / (256 * 8), 256, 0, stream>>>(x, xb);
    qkvg_kernel<<<g1, 256, 0, stream>>>(xb, wt, Qb, Kb, Vt);
  } else {
    qkv_kernel<<<g1, 256, 0, stream>>>(x, wt, Qb, Kb, Vt);
  }

  if (split) {
    attn_kernel<1><<<256, 512, 0, stream>>>(Qb, Kb, Vt, out, part0, part1, Ls, Ms);
    merge_kernel<<<(B_ * S_ * E_ / 8) / 256, 256, 0, stream>>>(out, part0, part1, Ls, Ms);
  } else {
    attn_kernel<0><<<128, 512, 0, stream>>>(Qb, Kb, Vt, out, nullptr, nullptr,
                                            nullptr, nullptr);
  }
}